// Round 3
// baseline (81.778 us; speedup 1.0000x reference)
//
#include <hip/hip_runtime.h>
#include <hip/hip_bf16.h>

// out[b] = SCALE * dot(x[b], sum_g wsums[g]),  SCALE = 1.5 * 0.5 = 0.75
// x: [1024, 8192] fp32 (streamed once), wsums: [32, 8192] fp32, out: [1024] fp32
//
// Structure: 2-kernel split.
//   A: fold wsums (32x8192) -> w_total (8192) in d_ws.  ~1 MiB read, trivial.
//   B: one block per row, float4-coalesced nontemporal x reads, cacheable
//      w_total reads (32 KiB, L1/L2-resident across all 1024 blocks).
// Floor: 33 MiB HBM read ~= 5.3 us @ 6.3 TB/s. Harness reset (~65 us of
// fillBuffer/restore traffic per iteration) dominates dur_us and is not
// controllable from here.

#define K_DIM 8192
#define G_DIM 32
#define SCALE 0.75f

// Native clang vector type — __builtin_nontemporal_load requires this
// (HIP_vector_type float4 is a struct and is rejected).
typedef float floatx4 __attribute__((ext_vector_type(4)));

__global__ void __launch_bounds__(256) wsum_fold_kernel(
    const float* __restrict__ wsums, float* __restrict__ w_total) {
    const int k = (blockIdx.x * 256 + threadIdx.x) * 4;
    floatx4 acc = {0.f, 0.f, 0.f, 0.f};
#pragma unroll
    for (int g = 0; g < G_DIM; ++g) {
        const floatx4 v = *reinterpret_cast<const floatx4*>(wsums + (size_t)g * K_DIM + k);
        acc += v;
    }
    *reinterpret_cast<floatx4*>(w_total + k) = acc;
}

__global__ void __launch_bounds__(256) row_dot_kernel(
    const float* __restrict__ x, const float* __restrict__ w_total,
    float* __restrict__ out) {
    const int row = blockIdx.x;
    const floatx4* xr = reinterpret_cast<const floatx4*>(x + (size_t)row * K_DIM);
    const floatx4* wt = reinterpret_cast<const floatx4*>(w_total);
    const int t = threadIdx.x;

    float acc = 0.f;
#pragma unroll
    for (int i = 0; i < K_DIM / (256 * 4); ++i) {
        const int idx = i * 256 + t;
        // x is streamed exactly once across the whole grid: nontemporal load
        // avoids evicting the shared w_total lines from L1/L2.
        const floatx4 xv = __builtin_nontemporal_load(xr + idx);
        const floatx4 wv = wt[idx];
        acc += xv.x * wv.x + xv.y * wv.y + xv.z * wv.z + xv.w * wv.w;
    }

    // Wave-64 shuffle reduction
#pragma unroll
    for (int off = 32; off > 0; off >>= 1)
        acc += __shfl_down(acc, off, 64);

    __shared__ float smem[4];
    const int lane = t & 63;
    const int wave = t >> 6;
    if (lane == 0) smem[wave] = acc;
    __syncthreads();
    if (t == 0) {
        out[row] = (smem[0] + smem[1] + smem[2] + smem[3]) * SCALE;
    }
}

extern "C" void kernel_launch(void* const* d_in, const int* in_sizes, int n_in,
                              void* d_out, int out_size, void* d_ws, size_t ws_size,
                              hipStream_t stream) {
    const float* x     = (const float*)d_in[0];   // [1024, 8192]
    const float* wsums = (const float*)d_in[1];   // [32, 8192]
    float* out         = (float*)d_out;           // [1024]
    float* w_total     = (float*)d_ws;            // 8192 floats scratch

    const int n_rows = in_sizes[0] / K_DIM;       // 1024

    wsum_fold_kernel<<<K_DIM / (256 * 4), 256, 0, stream>>>(wsums, w_total);
    row_dot_kernel<<<n_rows, 256, 0, stream>>>(x, w_total, out);
}

// Round 4
// 75.425 us; speedup vs baseline: 1.0842x; 1.0842x over previous
//
#include <hip/hip_runtime.h>
#include <hip/hip_bf16.h>

// out[b] = SCALE * dot(x[b], sum_g wsums[g]),  SCALE = 1.5 * 0.5 = 0.75
// x: [1024, 8192] fp32 (streamed once), wsums: [32, 8192] fp32, out: [1024] fp32
//
// 2-kernel split:
//   A: fold wsums (32x8192) -> w_total (8192) in d_ws. 32 blocks, one thread
//      per k (coalesced across the wave, 32 independent loads deep).
//      NOTE R3: 8-block float4 version starved parallelism (8 CUs).
//   B: one block per row, float4-coalesced x reads, cacheable w_total reads
//      (32 KiB, L1/L2-resident across all 1024 blocks).
//      NOTE R3: __builtin_nontemporal_load on x regressed 75.7->81.8 us; x is
//      single-pass so NT buys nothing. Reverted to plain loads.
// Floor: 33 MiB HBM read ~= 5.3 us @ 6.3 TB/s + 2 launches. Harness reset
// (~55-60 us of fillBuffer/restore per iteration) dominates dur_us.

#define K_DIM 8192
#define G_DIM 32
#define SCALE 0.75f

typedef float floatx4 __attribute__((ext_vector_type(4)));

// Kernel A: w_total[k] = sum_g wsums[g][k]. 32 blocks x 256 threads, thread
// per k; the 32 group loads are independent (fully unrolled) -> high MLP.
__global__ void __launch_bounds__(256) wsum_fold_kernel(
    const float* __restrict__ wsums, float* __restrict__ w_total) {
    const int k = blockIdx.x * 256 + threadIdx.x;
    float acc = 0.f;
#pragma unroll
    for (int g = 0; g < G_DIM; ++g) {
        acc += wsums[(size_t)g * K_DIM + k];
    }
    w_total[k] = acc;
}

// Kernel B: one block (256 threads) per row; 8 float4 loads of x per thread.
__global__ void __launch_bounds__(256) row_dot_kernel(
    const float* __restrict__ x, const float* __restrict__ w_total,
    float* __restrict__ out) {
    const int row = blockIdx.x;
    const floatx4* xr = reinterpret_cast<const floatx4*>(x + (size_t)row * K_DIM);
    const floatx4* wt = reinterpret_cast<const floatx4*>(w_total);
    const int t = threadIdx.x;

    float acc = 0.f;
#pragma unroll
    for (int i = 0; i < K_DIM / (256 * 4); ++i) {
        const int idx = i * 256 + t;
        const floatx4 xv = xr[idx];
        const floatx4 wv = wt[idx];
        acc += xv.x * wv.x + xv.y * wv.y + xv.z * wv.z + xv.w * wv.w;
    }

    // Wave-64 shuffle reduction
#pragma unroll
    for (int off = 32; off > 0; off >>= 1)
        acc += __shfl_down(acc, off, 64);

    __shared__ float smem[4];
    const int lane = t & 63;
    const int wave = t >> 6;
    if (lane == 0) smem[wave] = acc;
    __syncthreads();
    if (t == 0) {
        out[row] = (smem[0] + smem[1] + smem[2] + smem[3]) * SCALE;
    }
}

extern "C" void kernel_launch(void* const* d_in, const int* in_sizes, int n_in,
                              void* d_out, int out_size, void* d_ws, size_t ws_size,
                              hipStream_t stream) {
    const float* x     = (const float*)d_in[0];   // [1024, 8192]
    const float* wsums = (const float*)d_in[1];   // [32, 8192]
    float* out         = (float*)d_out;           // [1024]
    float* w_total     = (float*)d_ws;            // 8192 floats scratch

    const int n_rows = in_sizes[0] / K_DIM;       // 1024

    wsum_fold_kernel<<<K_DIM / 256, 256, 0, stream>>>(wsums, w_total);
    row_dot_kernel<<<n_rows, 256, 0, stream>>>(x, w_total, out);
}